// Round 1
// baseline (194.348 us; speedup 1.0000x reference)
//
#include <hip/hip_runtime.h>

#define N_PTS    20000
#define M_NODES  1024
#define BATCH    4
#define K_NN     50
#define D_MODEL  256
#define NPF      84      // num_pos_feats
#define BLOCK    256
#define SURV_CAP 512
#define WIN_HI   448

__device__ __forceinline__ float signed_angle(float ax, float ay, float az,
                                              float bx, float by, float bz) {
    float cx = ay * bz - az * by;
    float cy = az * bx - ax * bz;
    float cz = ax * by - ay * bx;
    float s = sqrtf(cx * cx + cy * cy + cz * cz);
    float c = ax * bx + ay * by + az * bz;
    float a = atan2f(s, c);
    return (c < 0.0f) ? -a : a;
}

__global__ __launch_bounds__(BLOCK) void ppf_kernel(
    const float* __restrict__ points,   // (B,N,3)
    const float* __restrict__ nodes,    // (B,M,3)
    const float* __restrict__ pnrm,     // (B,N,3)
    const float* __restrict__ nnrm,     // (B,M,3)
    const float* __restrict__ W,        // (4,256) row-major
    const float* __restrict__ bias,     // (256)
    float* __restrict__ out)            // glob (B,M,256) ++ pos (B,M,256)
{
    __shared__ unsigned short k16[N_PTS];          // 40000 B truncated d2 keys
    __shared__ unsigned long long skey[SURV_CAP];  // (d2bits<<32)|idx
    __shared__ int sidx[SURV_CAP];
    __shared__ int selidx[K_NN];
    __shared__ float f4[K_NN][4];
    __shared__ int red[4];
    __shared__ int s_pos;

    const int bm  = blockIdx.x;
    const int b   = bm >> 10;          // / M_NODES
    const int tid = threadIdx.x;

    const float* pts = points + (size_t)b * N_PTS * 3;
    const float* pnr = pnrm   + (size_t)b * N_PTS * 3;

    const float nx  = nodes[(size_t)bm * 3 + 0];
    const float ny  = nodes[(size_t)bm * 3 + 1];
    const float nz  = nodes[(size_t)bm * 3 + 2];
    const float n1x = nnrm[(size_t)bm * 3 + 0];
    const float n1y = nnrm[(size_t)bm * 3 + 1];
    const float n1z = nnrm[(size_t)bm * 3 + 2];

    // ---- Phase A: squared distances -> 16-bit monotone keys in LDS ----
    for (int i = tid; i < N_PTS; i += BLOCK) {
        float dx = pts[i * 3 + 0] - nx;
        float dy = pts[i * 3 + 1] - ny;
        float dz = pts[i * 3 + 2] - nz;
        float d2 = dx * dx + dy * dy + dz * dz;
        k16[i] = (unsigned short)(__float_as_uint(d2) >> 16);
    }
    __syncthreads();

    // count of keys strictly < t, broadcast to all threads
    auto count_less = [&](unsigned int t) -> int {
        const unsigned int* k32 = (const unsigned int*)k16;
        int c = 0;
        for (int j = tid; j < N_PTS / 2; j += BLOCK) {
            unsigned int u = k32[j];
            c += (int)((u & 0xFFFFu) < t) + (int)((u >> 16) < t);
        }
        for (int off = 32; off > 0; off >>= 1) c += __shfl_down(c, off);
        if ((tid & 63) == 0) red[tid >> 6] = c;
        __syncthreads();
        int total = red[0] + red[1] + red[2] + red[3];
        __syncthreads();
        return total;
    };

    // ---- Phase B: binary search for threshold with 50 <= cnt <= WIN_HI ----
    unsigned int lo = 0, hi = 0x7F80u;  // count(<lo)=0, count(<hi)=N_PTS
    unsigned int t = hi;
    int cnt = -1;
    for (int it = 0; it < 18; ++it) {
        if (hi - lo <= 1u) break;
        unsigned int mid = (lo + hi) >> 1;
        int c = count_less(mid);
        if (c >= K_NN && c <= WIN_HI) { t = mid; cnt = c; break; }
        if (c < K_NN) lo = mid; else hi = mid;
    }
    if (cnt < 0) { t = hi; cnt = count_less(t); }
    if (cnt > SURV_CAP) cnt = SURV_CAP;  // safety clamp (pathological ties only)

    // ---- Phase C: compact survivor indices ----
    if (tid == 0) s_pos = 0;
    __syncthreads();
    for (int i = tid; i < N_PTS; i += BLOCK) {
        if ((unsigned int)k16[i] < t) {
            int p = atomicAdd(&s_pos, 1);
            if (p < SURV_CAP) sidx[p] = i;
        }
    }
    __syncthreads();
    int nsurv = s_pos < SURV_CAP ? s_pos : SURV_CAP;

    // ---- Phase D: exact f32 keys for survivors ----
    for (int s = tid; s < nsurv; s += BLOCK) {
        int i = sidx[s];
        float dx = pts[i * 3 + 0] - nx;
        float dy = pts[i * 3 + 1] - ny;
        float dz = pts[i * 3 + 2] - nz;
        float d2 = dx * dx + dy * dy + dz * dz;
        skey[s] = ((unsigned long long)__float_as_uint(d2) << 32) | (unsigned int)i;
    }
    __syncthreads();

    // ---- Phase E: exact rank selection of the 50 nearest (ties -> low idx) ----
    for (int s = tid; s < nsurv; s += BLOCK) {
        unsigned long long mykey = skey[s];
        int rank = 0;
        for (int j = 0; j < nsurv; ++j) rank += (int)(skey[j] < mykey);
        if (rank < K_NN) selidx[rank] = (int)(mykey & 0xFFFFFFFFull);
    }
    __syncthreads();

    // ---- Phase F: PPF features for the 50 selected neighbors ----
    if (tid < K_NN) {
        int i = selidx[tid];
        float px = pts[i * 3 + 0], py = pts[i * 3 + 1], pz = pts[i * 3 + 2];
        float qx = pnr[i * 3 + 0], qy = pnr[i * 3 + 1], qz = pnr[i * 3 + 2];
        float ijx = px - nx, ijy = py - ny, ijz = pz - nz;
        float d = sqrtf(ijx * ijx + ijy * ijy + ijz * ijz);  // SCALE = 1
        float a1 = signed_angle(ijx, ijy, ijz, n1x, n1y, n1z);
        float a2 = signed_angle(-ijx, -ijy, -ijz, qx, qy, qz);
        float a3 = signed_angle(n1x, n1y, n1z, qx, qy, qz);
        f4[tid][0] = d;
        f4[tid][1] = a1;
        f4[tid][2] = a2;
        f4[tid][3] = a3;
    }
    __syncthreads();

    // ---- Phase G: glob[d] = max_k (f4[k] . W[:,d]) + b[d] ----
    {
        int d = tid;
        float w0 = W[d], w1 = W[D_MODEL + d], w2 = W[2 * D_MODEL + d], w3 = W[3 * D_MODEL + d];
        float mx = -INFINITY;
        #pragma unroll 5
        for (int k = 0; k < K_NN; ++k) {
            float v = f4[k][0] * w0 + f4[k][1] * w1 + f4[k][2] * w2 + f4[k][3] * w3;
            mx = fmaxf(mx, v);
        }
        out[(size_t)bm * D_MODEL + d] = mx + bias[d];
    }

    // ---- Phase H: sinusoidal positional embedding ----
    {
        int d = tid;
        float v = 0.0f;
        if (d < 3 * NPF) {
            int c = d / NPF;
            int r = d - c * NPF;
            int i = r >> 1;
            float nc = (c == 0) ? nx : ((c == 1) ? ny : nz);
            // dim_t = 10000^(i/42); x = nc / dim_t
            const float L2_10000 = 13.287712379549449f;
            float tinv = exp2f(-L2_10000 * (float)i / 42.0f);
            float x = nc * tinv;
            v = (r & 1) ? cosf(x) : sinf(x);
        }
        out[(size_t)BATCH * M_NODES * D_MODEL + (size_t)bm * D_MODEL + d] = v;
    }
}

extern "C" void kernel_launch(void* const* d_in, const int* in_sizes, int n_in,
                              void* d_out, int out_size, void* d_ws, size_t ws_size,
                              hipStream_t stream) {
    const float* points = (const float*)d_in[0];
    const float* nodes  = (const float*)d_in[1];
    const float* pn     = (const float*)d_in[2];
    const float* nn     = (const float*)d_in[3];
    const float* W      = (const float*)d_in[4];
    const float* bias   = (const float*)d_in[5];
    float* out = (float*)d_out;

    dim3 grid(BATCH * M_NODES);
    dim3 block(BLOCK);
    ppf_kernel<<<grid, block, 0, stream>>>(points, nodes, pn, nn, W, bias, out);
}